// Round 4
// baseline (364.162 us; speedup 1.0000x reference)
//
#include <hip/hip_runtime.h>

// Bilinear scatter-add, v9.
// v8 post-mortem: the 896MB/137us fillBufferAligned in top-5 is the HARNESS
// workspace re-poison -- fixed cost, every iteration, untouchable. accum
// dropped below the 134us cutoff (~125us), fill ~70us. accum is still ~3x
// off its 31us HBM floor (FETCH 197MB): per-wave dependent chain
// cnt->headers->rows repeated serially, plus 25% imbalance from binLin%8
// (wave0 owns 4 bins, others 3).
//
// v9 accum: stage ALL 25 halo bins' headers+counts into LDS once
// (cooperative, coalesced), one barrier; main loop reads headers from LDS
// (broadcast, no global header/cnt loads on the critical path) and splits
// each bin's entries per-wave by range [n*wid/8, n*(wid+1)/8) -- perfectly
// balanced, ~5-6 independent 448B row loads per bin per wave, unroll-4
// pipeline. LDS header array reused as the merge buffer (25.6 KB total).
// v9 fill: 4 points/thread (two float4 loads) -> 4 independent RMWs in
// flight per thread.

#define D     112
#define D2    56            // float2 per feature row
#define H     64
#define W     176
#define HW    (H * W)       // 11264
#define CAP   128           // mean 44.4/bin, sigma 6.7 -> +12 sigma
#define CSTR  16            // counter stride in ints = 64B line
#define TY    4
#define TX    4
#define GX    (W / TX)      // 44
#define GY    (H / TY)      // 16
#define NCELL (TY * TX)     // 16
#define NW    8             // waves per accum block
#define NBIN  25            // 5x5 halo
#define NSLOT (NBIN * CAP)  // 3200 slots, 25.6 KB

__device__ __forceinline__ void fill_one(int p, float x, float y,
                                         int* cnt, uint2* bucket)
{
    float xf = floorf(x), yf = floorf(y);
    float wx = x - xf,    wy = y - yf;
    int x0 = min(max((int)xf, 0), W - 1);
    int y0 = min(max((int)yf, 0), H - 1);
    int bin = y0 * W + x0;
    unsigned qw = (__float2uint_rn(wy * 65535.0f) << 16)
                |  __float2uint_rn(wx * 65535.0f);
    int i = atomicAdd(&cnt[bin * CSTR], 1);
    if (i < CAP) bucket[(size_t)bin * CAP + i] = make_uint2((unsigned)p, qw);
}

__global__ __launch_bounds__(256) void fill_kernel(
    const float2* __restrict__ pos,   // [N]
    int* __restrict__ cnt,            // [HW*CSTR], pre-zeroed
    uint2* __restrict__ bucket,       // [HW*CAP]
    int N)
{
    int i = blockIdx.x * blockDim.x + threadIdx.x;
    int p0 = 4 * i;
    if (p0 >= N) return;
    const float4* p4 = (const float4*)pos;
    if (p0 + 3 < N) {
        float4 a = p4[2 * i];
        float4 b = p4[2 * i + 1];
        fill_one(p0,     a.x, a.y, cnt, bucket);
        fill_one(p0 + 1, a.z, a.w, cnt, bucket);
        fill_one(p0 + 2, b.x, b.y, cnt, bucket);
        fill_one(p0 + 3, b.z, b.w, cnt, bucket);
    } else {
        for (int k = 0; k < 4 && p0 + k < N; ++k) {
            float2 q = pos[p0 + k];
            fill_one(p0 + k, q.x, q.y, cnt, bucket);
        }
    }
}

// One block per 4x4 cell tile; halo = 5x5 bins. A point in bin (gby,gbx)
// with weights (wx,wy) contributes (dy?wy:1-wy)*(dx?wx:1-wx)*feat[p] to
// cell (gby+dy,gbx+dx). Bin loops fully unrolled -> acc indices static.
__global__ __launch_bounds__(512, 6) void accum_kernel(
    const float* __restrict__ feat,      // [N, D]
    const int* __restrict__ cnt,
    const uint2* __restrict__ bucket,
    float* __restrict__ out)             // [H*W, D]
{
    const int tile = blockIdx.x;
    const int ty0  = (tile / GX) * TY;
    const int tx0  = (tile % GX) * TX;
    const int t    = threadIdx.x;
    const int wid  = t >> 6;
    const int lane = t & 63;
    const bool act = lane < D2;

    __shared__ int sn[NBIN];
    __shared__ __align__(16) char smem[NSLOT * sizeof(uint2)];  // 25.6 KB
    uint2* shdr = (uint2*)smem;

    // stage per-bin counts
    if (t < NBIN) {
        int by = t / 5 - 1, bx = t % 5 - 1;
        int gby = ty0 + by, gbx = tx0 + bx;
        int n = 0;
        if (gby >= 0 && gbx >= 0 && gbx < W)   // gby<H always
            n = min(cnt[(gby * W + gbx) * CSTR], CAP);
        sn[t] = n;
    }
    __syncthreads();

    // stage all headers: slot i = bin (i>>7), entry (i&127); coalesced
    for (int i = t; i < NSLOT; i += 512) {
        int b = i >> 7, s = i & (CAP - 1);
        if (s < sn[b]) {
            int by = b / 5 - 1, bx = b % 5 - 1;
            int gbin = (ty0 + by) * W + (tx0 + bx);
            shdr[i] = bucket[(size_t)gbin * CAP + s];
        }
    }
    __syncthreads();

    float2 acc[NCELL];
#pragma unroll
    for (int c = 0; c < NCELL; ++c) acc[c] = make_float2(0.0f, 0.0f);

#pragma unroll
    for (int by = -1; by < TY; ++by) {
#pragma unroll
        for (int bx = -1; bx < TX; ++bx) {
            const int b  = (by + 1) * 5 + (bx + 1);   // compile-time
            const int n  = sn[b];
            const int lo = (n * wid) >> 3;
            const int hi = (n * (wid + 1)) >> 3;
            const uint2* hb = shdr + b * CAP;

#pragma unroll 4
            for (int e = lo; e < hi; ++e) {
                uint2 en = hb[e];                     // LDS broadcast
                float wx = (float)(en.y & 0xffffu) * (1.0f / 65535.0f);
                float wy = (float)(en.y >> 16)     * (1.0f / 65535.0f);
                float2 f = make_float2(0.0f, 0.0f);
                if (act)
                    f = ((const float2*)(feat + (size_t)en.x * D))[lane];
                float ax = 1.0f - wx, ay = 1.0f - wy;
#pragma unroll
                for (int dy = 0; dy < 2; ++dy) {
                    const int cy = by + dy;           // compile-time
                    if (cy < 0 || cy >= TY) continue;
                    const float fy = dy ? wy : ay;
#pragma unroll
                    for (int dx = 0; dx < 2; ++dx) {
                        const int cx = bx + dx;       // compile-time
                        if (cx < 0 || cx >= TX) continue;
                        const float fw = fy * (dx ? wx : ax);
                        const int c = cy * TX + cx;
                        acc[c].x = fmaf(fw, f.x, acc[c].x);
                        acc[c].y = fmaf(fw, f.y, acc[c].y);
                    }
                }
            }
        }
    }

    // protect LDS reuse (shdr dead from here), then cross-wave merge:
    // waves 0-3 -> copy 0, waves 4-7 -> copy 1, serial depth 4.
    __syncthreads();
    float2 (*sacc)[NCELL][D2] = reinterpret_cast<float2 (*)[NCELL][D2]>(smem);
    const int half = wid >> 2;
    const int sub  = wid & 3;

    for (int w = 0; w < 4; ++w) {
        if (sub == w && act) {
            if (w == 0) {
#pragma unroll
                for (int c = 0; c < NCELL; ++c) sacc[half][c][lane] = acc[c];
            } else {
#pragma unroll
                for (int c = 0; c < NCELL; ++c) {
                    float2 v = sacc[half][c][lane];
                    v.x += acc[c].x; v.y += acc[c].y;
                    sacc[half][c][lane] = v;
                }
            }
        }
        __syncthreads();
    }

    // store: wave w stores cells 2w and 2w+1; 448B coalesced per cell
    if (act) {
#pragma unroll
        for (int k = 0; k < 2; ++k) {
            const int c  = wid * 2 + k;
            const int cy = c / TX, cx = c % TX;
            float2 v0 = sacc[0][c][lane];
            float2 v1 = sacc[1][c][lane];
            float2* dst = (float2*)(out + ((size_t)(ty0 + cy) * W + (tx0 + cx)) * D);
            dst[lane] = make_float2(v0.x + v1.x, v0.y + v1.y);
        }
    }
}

extern "C" void kernel_launch(void* const* d_in, const int* in_sizes, int n_in,
                              void* d_out, int out_size, void* d_ws, size_t ws_size,
                              hipStream_t stream) {
    const float2* pos = (const float2*)d_in[0];
    const float* feat = (const float*)d_in[1];
    float* out        = (float*)d_out;

    const int N = in_sizes[0] / 2;

    int* cnt      = (int*)d_ws;
    uint2* bucket = (uint2*)((char*)d_ws + (size_t)HW * CSTR * sizeof(int));
    // ws use: 11264*16*4 B (720 KB) + 11264*128*8 B (11.5 MB) = 12.2 MB

    hipMemsetAsync(cnt, 0, (size_t)HW * CSTR * sizeof(int), stream);

    int nq = (N + 3) / 4;
    fill_kernel<<<(nq + 255) / 256, 256, 0, stream>>>(pos, cnt, bucket, N);

    accum_kernel<<<GY * GX, 512, 0, stream>>>(feat, cnt, bucket, out);
}